// Round 2
// baseline (8958.330 us; speedup 1.0000x reference)
//
#include <hip/hip_runtime.h>
#include <hip/hip_bf16.h>
#include <cstdint>

using ull = unsigned long long;

#define NB 4
#define NA 7500
#define PRE 2000
#define POST 1000

// ----------------------------------------------------------------------------
// Generic 3x3 conv, pad=1, stride STRIDE, optional relu. Block: 16x16 spatial
// tile x 32 output channels. 256 threads: 8x8 spatial threads (2x2 px each) x
// 4 co-groups (8 co each).
// ----------------------------------------------------------------------------
template<int CIN, int COUT, int STRIDE, int CI_CHUNK>
__global__ __launch_bounds__(256)
void conv3x3_k(const float* __restrict__ in, const float* __restrict__ w,
               float* __restrict__ out, int Hin, int Win, int Hout, int Wout,
               int ntx, int do_relu)
{
    constexpr int IN_T = STRIDE * 15 + 3;
    __shared__ float s_in[CI_CHUNK][IN_T][IN_T + 1];
    __shared__ float s_w[CI_CHUNK][9][32];

    const int tid = threadIdx.x;
    const int txx = tid & 7, tyy = (tid >> 3) & 7, cog = tid >> 6;
    const int ty0 = (blockIdx.x / ntx) * 16, tx0 = (blockIdx.x % ntx) * 16;
    const int co0 = blockIdx.y * 32;
    const int n = blockIdx.z;

    float acc[2][2][8];
#pragma unroll
    for (int a = 0; a < 2; a++)
#pragma unroll
        for (int b = 0; b < 2; b++)
#pragma unroll
            for (int q = 0; q < 8; q++) acc[a][b][q] = 0.f;

    const float* inN = in + (size_t)n * CIN * Hin * Win;

    for (int ci0 = 0; ci0 < CIN; ci0 += CI_CHUNK) {
        for (int idx = tid; idx < CI_CHUNK * IN_T * IN_T; idx += 256) {
            int ci = idx / (IN_T * IN_T);
            int rr = (idx / IN_T) % IN_T;
            int cc = idx % IN_T;
            int gy = ty0 * STRIDE - 1 + rr;
            int gx = tx0 * STRIDE - 1 + cc;
            float v = 0.f;
            if ((unsigned)gy < (unsigned)Hin && (unsigned)gx < (unsigned)Win)
                v = inN[(size_t)(ci0 + ci) * Hin * Win + (size_t)gy * Win + gx];
            s_in[ci][rr][cc] = v;
        }
        for (int idx = tid; idx < CI_CHUNK * 9 * 32; idx += 256) {
            int co = idx & 31;
            int rest = idx >> 5;
            int kk = rest % 9, ci = rest / 9;
            s_w[ci][kk][co] = w[((size_t)(co0 + co) * CIN + ci0 + ci) * 9 + kk];
        }
        __syncthreads();
#pragma unroll
        for (int ci = 0; ci < CI_CHUNK; ++ci) {
#pragma unroll
            for (int kk = 0; kk < 9; ++kk) {
                const int ky = kk / 3, kx = kk % 3;
                float v[2][2];
#pragma unroll
                for (int dy = 0; dy < 2; dy++)
#pragma unroll
                    for (int dx = 0; dx < 2; dx++)
                        v[dy][dx] = s_in[ci][(2 * tyy + dy) * STRIDE + ky]
                                        [(2 * txx + dx) * STRIDE + kx];
                const float* wp = &s_w[ci][kk][cog * 8];
#pragma unroll
                for (int q = 0; q < 8; q++) {
                    float wv = wp[q];
#pragma unroll
                    for (int dy = 0; dy < 2; dy++)
#pragma unroll
                        for (int dx = 0; dx < 2; dx++)
                            acc[dy][dx][q] += v[dy][dx] * wv;
                }
            }
        }
        __syncthreads();
    }
#pragma unroll
    for (int dy = 0; dy < 2; dy++)
#pragma unroll
        for (int dx = 0; dx < 2; dx++) {
            int oy = ty0 + 2 * tyy + dy, ox = tx0 + 2 * txx + dx;
            if (oy < Hout && ox < Wout) {
#pragma unroll
                for (int q = 0; q < 8; q++) {
                    int co = co0 + cog * 8 + q;
                    float r = acc[dy][dx][q];
                    if (do_relu) r = fmaxf(r, 0.f);
                    out[((size_t)n * COUT + co) * Hout * Wout + (size_t)oy * Wout + ox] = r;
                }
            }
        }
}

// ----------------------------------------------------------------------------
// 1x1 heads: obj (3ch) + reg (12ch). Writes scores in anchor order and deltas.
// ----------------------------------------------------------------------------
__global__ __launch_bounds__(256)
void rpn_head_k(const float* __restrict__ t, const float* __restrict__ wobj,
                const float* __restrict__ wreg, float* __restrict__ scores,
                float* __restrict__ deltas)
{
    __shared__ float sw[15][256];
    int tid = threadIdx.x;
    for (int i = tid; i < 15 * 256; i += 256) {
        int k = i >> 8, ci = i & 255;
        sw[k][ci] = (k < 3) ? wobj[k * 256 + ci] : wreg[(k - 3) * 256 + ci];
    }
    __syncthreads();
    int p = blockIdx.x * 256 + tid;
    if (p < NB * 2500) {
        int b = p / 2500, yx = p % 2500;
        float acc[15];
#pragma unroll
        for (int k = 0; k < 15; k++) acc[k] = 0.f;
        const float* tb = t + ((size_t)b * 256) * 2500 + yx;
        for (int ci = 0; ci < 256; ++ci) {
            float v = tb[(size_t)ci * 2500];
#pragma unroll
            for (int k = 0; k < 15; k++) acc[k] += v * sw[k][ci];
        }
#pragma unroll
        for (int k = 0; k < 3; k++)
            scores[(size_t)b * NA + yx * 3 + k] = acc[k];
#pragma unroll
        for (int k = 0; k < 3; k++)
#pragma unroll
            for (int c = 0; c < 4; c++)
                deltas[((size_t)b * NA + (size_t)yx * 3 + k) * 4 + c] = acc[3 + k * 4 + c];
    }
}

// ----------------------------------------------------------------------------
// Box decode: anchors generated analytically (all coords exact in f32).
// ----------------------------------------------------------------------------
__global__ void decode_k(const float* __restrict__ deltas, float* __restrict__ boxes)
{
    int g = blockIdx.x * 256 + threadIdx.x;
    if (g >= NB * NA) return;
    int a = g % NA;
    int k = a % 3, x = (a / 3) % 50, y = a / 150;
    float s = (k == 0) ? 64.f : (k == 1) ? 128.f : 256.f;
    float cxa = x * 16.f + 8.f, cya = y * 16.f + 8.f;
    const float* d = deltas + (size_t)g * 4;
    float dx = d[0], dy = d[1], dw = d[2], dh = d[3];
    const float clampv = 4.135166556742356f;  // log(1000/16)
    dw = fminf(dw, clampv);
    dh = fminf(dh, clampv);
    float cx = dx * s + cxa, cy = dy * s + cya;
    float w = expf(dw) * s, h = expf(dh) * s;
    float b0 = cx - w * 0.5f, b1 = cy - h * 0.5f;
    float b2 = cx + w * 0.5f, b3 = cy + h * 0.5f;
    float* o = boxes + (size_t)g * 4;
    o[0] = fminf(fmaxf(b0, 0.f), 800.f);
    o[1] = fminf(fmaxf(b1, 0.f), 800.f);
    o[2] = fminf(fmaxf(b2, 0.f), 800.f);
    o[3] = fminf(fmaxf(b3, 0.f), 800.f);
}

// ----------------------------------------------------------------------------
// Top-2000 via bitonic sort of packed keys: hi 32 = ~sortable(score)
// (descending score), lo 32 = index (ascending ties) -> matches lax.top_k.
// ----------------------------------------------------------------------------
__global__ __launch_bounds__(1024)
void topk_k(const float* __restrict__ scores, const float* __restrict__ boxes,
            float* __restrict__ topb)
{
    __shared__ ull key[8192];
    int b = blockIdx.x, tid = threadIdx.x;
    for (int i = tid; i < 8192; i += 1024) {
        ull kv = ~0ull;
        if (i < NA) {
            unsigned u = __float_as_uint(scores[(size_t)b * NA + i]);
            unsigned m = u ^ (((int)u < 0) ? 0xFFFFFFFFu : 0x80000000u);
            kv = ((ull)(~m) << 32) | (unsigned)i;
        }
        key[i] = kv;
    }
    __syncthreads();
    for (int k = 2; k <= 8192; k <<= 1) {
        for (int j = k >> 1; j > 0; j >>= 1) {
            for (int i = tid; i < 8192; i += 1024) {
                int ixj = i ^ j;
                if (ixj > i) {
                    ull a = key[i], c = key[ixj];
                    bool sw = ((i & k) == 0) ? (a > c) : (a < c);
                    if (sw) { key[i] = c; key[ixj] = a; }
                }
            }
            __syncthreads();
        }
    }
    for (int i = tid; i < PRE; i += 1024) {
        int idx = (int)(key[i] & 0xFFFFFFFFull);
#pragma unroll
        for (int c = 0; c < 4; c++)
            topb[((size_t)b * PRE + i) * 4 + c] = boxes[((size_t)b * NA + idx) * 4 + c];
    }
}

// ----------------------------------------------------------------------------
// IoU > 0.7 bitmask, diagonal excluded. thread = (batch, row i, 64-col word).
// ----------------------------------------------------------------------------
__global__ void iou_mask_k(const float* __restrict__ topb, ull* __restrict__ mask)
{
    int g = blockIdx.x * 256 + threadIdx.x;
    if (g >= NB * PRE * 32) return;
    int b = g / (PRE * 32);
    int r = g % (PRE * 32);
    int i = r >> 5, w = r & 31;
    const float* bi = topb + ((size_t)b * PRE + i) * 4;
    float x1 = bi[0], y1 = bi[1], x2 = bi[2], y2 = bi[3];
    float ai = (x2 - x1) * (y2 - y1);
    ull bits = 0;
    int j0 = w * 64;
    for (int jj = 0; jj < 64; ++jj) {
        int j = j0 + jj;
        if (j >= PRE) break;
        if (j == i) continue;
        const float* bj = topb + ((size_t)b * PRE + j) * 4;
        float xx1 = fmaxf(x1, bj[0]);
        float yy1 = fmaxf(y1, bj[1]);
        float xx2 = fminf(x2, bj[2]);
        float yy2 = fminf(y2, bj[3]);
        float iw = fmaxf(xx2 - xx1, 0.f), ih = fmaxf(yy2 - yy1, 0.f);
        float inter = iw * ih;
        float aj = (bj[2] - bj[0]) * (bj[3] - bj[1]);
        float iou = inter / (ai + aj - inter + 1e-6f);
        if (iou > 0.7f) bits |= (1ull << jj);
    }
    mask[((size_t)b * PRE + i) * 32 + w] = bits;
}

// ----------------------------------------------------------------------------
// Sequential greedy NMS scan (one wave per batch), then emit 1000 props:
// kept (sorted order) padded with suppressed indices ascending.
// ----------------------------------------------------------------------------
__global__ __launch_bounds__(64)
void nms_scan_k(const ull* __restrict__ mask, const float* __restrict__ topb,
                float* __restrict__ props)
{
    __shared__ ull rem[32];
    __shared__ int klist[PRE];
    __shared__ int slist[PRE];
    __shared__ int nks;
    int b = blockIdx.x, lane = threadIdx.x;
    if (lane < 32) rem[lane] = 0ull;
    __syncthreads();
    int nk = 0;
    for (int i = 0; i < PRE; ++i) {
        bool keep = ((rem[i >> 6] >> (i & 63)) & 1ull) == 0ull;
        if (keep) {
            if (lane < 32) rem[lane] |= mask[((size_t)b * PRE + i) * 32 + lane];
            if (lane == 0) klist[nk] = i;
            nk++;
        }
        __syncthreads();
    }
    if (lane == 0) {
        int ns = 0;
        for (int i = 0; i < PRE; ++i)
            if ((rem[i >> 6] >> (i & 63)) & 1ull) slist[ns++] = i;
        nks = nk;
    }
    __syncthreads();
    int nkk = nks;
    for (int j = lane; j < POST; j += 64) {
        int kf = (j < nkk) ? klist[j] : slist[j - nkk];
#pragma unroll
        for (int c = 0; c < 4; c++)
            props[((size_t)b * POST + j) * 4 + c] = topb[((size_t)b * PRE + kf) * 4 + c];
    }
}

// ----------------------------------------------------------------------------
// ROI align: one block per (b, p); 14x14 samples -> 7x7 bins, 256 channels.
// ----------------------------------------------------------------------------
__global__ __launch_bounds__(256)
void roi_align_k(const float* __restrict__ feat, const float* __restrict__ props,
                 float* __restrict__ flat)
{
    __shared__ int sy0[14], sy1[14], sx0[14], sx1[14];
    __shared__ float swy[14], swx[14];
    int r = blockIdx.x, tid = threadIdx.x;
    int b = r / POST;
    const float* box = props + (size_t)r * 4;
    if (tid < 14) {
        float x1 = box[0] * 0.0625f, y1 = box[1] * 0.0625f;
        float x2 = box[2] * 0.0625f, y2 = box[3] * 0.0625f;
        float bw = (x2 - x1) / 7.0f, bh = (y2 - y1) / 7.0f;
        float off = ((float)tid + 0.5f) * 0.5f;
        float ys = y1 + off * bh;
        float xs = x1 + off * bw;
        float y0f = fminf(fmaxf(floorf(ys), 0.f), 49.f);
        float x0f = fminf(fmaxf(floorf(xs), 0.f), 49.f);
        swy[tid] = fminf(fmaxf(ys - y0f, 0.f), 1.f);
        swx[tid] = fminf(fmaxf(xs - x0f, 0.f), 1.f);
        sy0[tid] = (int)y0f;
        sy1[tid] = min((int)y0f + 1, 49);
        sx0[tid] = (int)x0f;
        sx1[tid] = min((int)x0f + 1, 49);
    }
    __syncthreads();
    const float* fb = feat + (size_t)b * 256 * 2500;
    for (int o = tid; o < 12544; o += 256) {
        int c = o / 49, rem2 = o % 49;
        int py = rem2 / 7, px = rem2 % 7;
        const float* fp = fb + (size_t)c * 2500;
        float s = 0.f;
#pragma unroll
        for (int sy = 0; sy < 2; ++sy) {
            int iy = py * 2 + sy;
            float wy = swy[iy];
            int yr0 = sy0[iy] * 50, yr1 = sy1[iy] * 50;
#pragma unroll
            for (int sx = 0; sx < 2; ++sx) {
                int ix = px * 2 + sx;
                float wx = swx[ix];
                float f00 = fp[yr0 + sx0[ix]];
                float f01 = fp[yr0 + sx1[ix]];
                float f10 = fp[yr1 + sx0[ix]];
                float f11 = fp[yr1 + sx1[ix]];
                s += f00 * (1.f - wy) * (1.f - wx) + f01 * (1.f - wy) * wx
                   + f10 * wy * (1.f - wx) + f11 * wy * wx;
            }
        }
        flat[(size_t)r * 12544 + o] = s * 0.25f;
    }
}

// ----------------------------------------------------------------------------
// f32 GEMM: C[M,N] = relu(A[M,K] @ W[N,K]^T + bias). 128x128 tile, BK=16,
// 256 threads, 8x8 per thread.
// ----------------------------------------------------------------------------
template<int RELU>
__global__ __launch_bounds__(256)
void gemm_bias_k(const float* __restrict__ A, const float* __restrict__ W,
                 const float* __restrict__ bias, float* __restrict__ C,
                 int M, int N, int K)
{
    __shared__ __align__(16) float As[16][132];
    __shared__ __align__(16) float Ws[16][132];
    int tid = threadIdx.x;
    int m0 = blockIdx.y * 128, n0 = blockIdx.x * 128;
    int tx = tid % 16, ty = tid / 16;
    float acc[8][8];
#pragma unroll
    for (int i = 0; i < 8; i++)
#pragma unroll
        for (int j = 0; j < 8; j++) acc[i][j] = 0.f;

    int c4 = (tid & 3) * 4;
    int rr = tid >> 2;
    for (int k0 = 0; k0 < K; k0 += 16) {
#pragma unroll
        for (int q = 0; q < 2; ++q) {
            int row = m0 + rr + q * 64;
            int arow = min(row, M - 1);
            float4 av = *reinterpret_cast<const float4*>(&A[(size_t)arow * K + k0 + c4]);
            As[c4 + 0][rr + q * 64] = av.x;
            As[c4 + 1][rr + q * 64] = av.y;
            As[c4 + 2][rr + q * 64] = av.z;
            As[c4 + 3][rr + q * 64] = av.w;
            int wrow = n0 + rr + q * 64;
            float4 wv = *reinterpret_cast<const float4*>(&W[(size_t)wrow * K + k0 + c4]);
            Ws[c4 + 0][rr + q * 64] = wv.x;
            Ws[c4 + 1][rr + q * 64] = wv.y;
            Ws[c4 + 2][rr + q * 64] = wv.z;
            Ws[c4 + 3][rr + q * 64] = wv.w;
        }
        __syncthreads();
#pragma unroll
        for (int kk = 0; kk < 16; ++kk) {
            float a8[8], w8[8];
#pragma unroll
            for (int i = 0; i < 8; i++) a8[i] = As[kk][ty * 8 + i];
#pragma unroll
            for (int j = 0; j < 8; j++) w8[j] = Ws[kk][tx * 8 + j];
#pragma unroll
            for (int i = 0; i < 8; i++)
#pragma unroll
                for (int j = 0; j < 8; j++) acc[i][j] += a8[i] * w8[j];
        }
        __syncthreads();
    }
#pragma unroll
    for (int i = 0; i < 8; i++) {
        int row = m0 + ty * 8 + i;
        if (row < M) {
#pragma unroll
            for (int j = 0; j < 8; j++) {
                int col = n0 + tx * 8 + j;
                float v = acc[i][j] + bias[col];
                if (RELU) v = fmaxf(v, 0.f);
                C[(size_t)row * N + col] = v;
            }
        }
    }
}

__global__ void rows_k(float* __restrict__ p)
{
    if (threadIdx.x < NB) p[threadIdx.x] = 1000.0f;
}

// ----------------------------------------------------------------------------
extern "C" void kernel_launch(void* const* d_in, const int* in_sizes, int n_in,
                              void* d_out, int out_size, void* d_ws, size_t ws_size,
                              hipStream_t stream)
{
    const float* images = (const float*)d_in[0];
    const float* W1 = (const float*)d_in[1];
    const float* W2 = (const float*)d_in[2];
    const float* W3 = (const float*)d_in[3];
    const float* W4 = (const float*)d_in[4];
    const float* Wrpn = (const float*)d_in[5];
    const float* Wobj = (const float*)d_in[6];
    const float* Wreg = (const float*)d_in[7];
    const float* Wfc1 = (const float*)d_in[8];
    const float* b1 = (const float*)d_in[9];
    const float* Wfc2 = (const float*)d_in[10];
    const float* b2 = (const float*)d_in[11];
    float* out = (float*)d_out;

    float* ws = (float*)d_ws;
    // Aliased layout (floats). Per-image conv buffers live inside the flat
    // region; they are dead before ROI-align writes flat.
    float* flat   = ws;                      // 50,176,000 (4000 x 12544)
    float* x1b    = ws;                      // 10,240,000 (1x64x400x400)
    float* x2b    = ws + 10240000;           //  5,120,000
    float* x3b    = ws + 15360000;           //  2,560,000
    float* feat   = ws + 50176000;           //  2,560,000 (4x256x50x50)
    float* t      = ws + 52736000;           //  2,560,000
    float* h1     = ws + 55296000;           //  4,096,000
    float* scores = ws + 59392000;           //     30,000
    float* deltas = ws + 59422000;           //    120,000
    float* boxes  = ws + 59542000;           //    120,000
    float* topb   = ws + 59662000;           //     32,000
    ull*   mask   = (ull*)(ws + 59694000);   //    256,000 ull (8B-aligned)
    float* props  = ws + 60206000;           //     16,000

    for (int n = 0; n < 4; ++n) {
        conv3x3_k<3, 64, 2, 3><<<dim3(25 * 25, 2, 1), 256, 0, stream>>>(
            images + (size_t)n * 3 * 800 * 800, W1, x1b, 800, 800, 400, 400, 25, 1);
        conv3x3_k<64, 128, 2, 8><<<dim3(13 * 13, 4, 1), 256, 0, stream>>>(
            x1b, W2, x2b, 400, 400, 200, 200, 13, 1);
        conv3x3_k<128, 256, 2, 8><<<dim3(7 * 7, 8, 1), 256, 0, stream>>>(
            x2b, W3, x3b, 200, 200, 100, 100, 7, 1);
        conv3x3_k<256, 256, 2, 8><<<dim3(4 * 4, 8, 1), 256, 0, stream>>>(
            x3b, W4, feat + (size_t)n * 256 * 2500, 100, 100, 50, 50, 4, 1);
    }
    conv3x3_k<256, 256, 1, 8><<<dim3(4 * 4, 8, 4), 256, 0, stream>>>(
        feat, Wrpn, t, 50, 50, 50, 50, 4, 1);
    rpn_head_k<<<40, 256, 0, stream>>>(t, Wobj, Wreg, scores, deltas);
    decode_k<<<(NB * NA + 255) / 256, 256, 0, stream>>>(deltas, boxes);
    topk_k<<<NB, 1024, 0, stream>>>(scores, boxes, topb);
    iou_mask_k<<<(NB * PRE * 32 + 255) / 256, 256, 0, stream>>>(topb, mask);
    nms_scan_k<<<NB, 64, 0, stream>>>(mask, topb, props);
    roi_align_k<<<NB * POST, 256, 0, stream>>>(feat, props, flat);
    gemm_bias_k<1><<<dim3(8, 32), 256, 0, stream>>>(flat, Wfc1, b1, h1, 4000, 1024, 12544);
    gemm_bias_k<1><<<dim3(8, 32), 256, 0, stream>>>(h1, Wfc2, b2, out, 4000, 1024, 1024);
    rows_k<<<1, 64, 0, stream>>>(out + 4096000);
}

// Round 4
// 7429.121 us; speedup vs baseline: 1.2058x; 1.2058x over previous
//
#include <hip/hip_runtime.h>
#include <hip/hip_bf16.h>
#include <cstdint>

using ull = unsigned long long;

#define NB 4
#define NA 7500
#define PRE 2000
#define POST 1000

typedef __attribute__((ext_vector_type(8))) short short8v;
typedef __attribute__((ext_vector_type(4))) float f32x4;

#define GLOBAL_AS __attribute__((address_space(1)))
#define LDS_AS __attribute__((address_space(3)))

// ----------------------------------------------------------------------------
// Generic 3x3 conv, pad=1, stride STRIDE, optional relu (f32, unchanged).
// ----------------------------------------------------------------------------
template<int CIN, int COUT, int STRIDE, int CI_CHUNK>
__global__ __launch_bounds__(256)
void conv3x3_k(const float* __restrict__ in, const float* __restrict__ w,
               float* __restrict__ out, int Hin, int Win, int Hout, int Wout,
               int ntx, int do_relu)
{
    constexpr int IN_T = STRIDE * 15 + 3;
    __shared__ float s_in[CI_CHUNK][IN_T][IN_T + 1];
    __shared__ float s_w[CI_CHUNK][9][32];

    const int tid = threadIdx.x;
    const int txx = tid & 7, tyy = (tid >> 3) & 7, cog = tid >> 6;
    const int ty0 = (blockIdx.x / ntx) * 16, tx0 = (blockIdx.x % ntx) * 16;
    const int co0 = blockIdx.y * 32;
    const int n = blockIdx.z;

    float acc[2][2][8];
#pragma unroll
    for (int a = 0; a < 2; a++)
#pragma unroll
        for (int b = 0; b < 2; b++)
#pragma unroll
            for (int q = 0; q < 8; q++) acc[a][b][q] = 0.f;

    const float* inN = in + (size_t)n * CIN * Hin * Win;

    for (int ci0 = 0; ci0 < CIN; ci0 += CI_CHUNK) {
        for (int idx = tid; idx < CI_CHUNK * IN_T * IN_T; idx += 256) {
            int ci = idx / (IN_T * IN_T);
            int rr = (idx / IN_T) % IN_T;
            int cc = idx % IN_T;
            int gy = ty0 * STRIDE - 1 + rr;
            int gx = tx0 * STRIDE - 1 + cc;
            float v = 0.f;
            if ((unsigned)gy < (unsigned)Hin && (unsigned)gx < (unsigned)Win)
                v = inN[(size_t)(ci0 + ci) * Hin * Win + (size_t)gy * Win + gx];
            s_in[ci][rr][cc] = v;
        }
        for (int idx = tid; idx < CI_CHUNK * 9 * 32; idx += 256) {
            int co = idx & 31;
            int rest = idx >> 5;
            int kk = rest % 9, ci = rest / 9;
            s_w[ci][kk][co] = w[((size_t)(co0 + co) * CIN + ci0 + ci) * 9 + kk];
        }
        __syncthreads();
#pragma unroll
        for (int ci = 0; ci < CI_CHUNK; ++ci) {
#pragma unroll
            for (int kk = 0; kk < 9; ++kk) {
                const int ky = kk / 3, kx = kk % 3;
                float v[2][2];
#pragma unroll
                for (int dy = 0; dy < 2; dy++)
#pragma unroll
                    for (int dx = 0; dx < 2; dx++)
                        v[dy][dx] = s_in[ci][(2 * tyy + dy) * STRIDE + ky]
                                        [(2 * txx + dx) * STRIDE + kx];
                const float* wp = &s_w[ci][kk][cog * 8];
#pragma unroll
                for (int q = 0; q < 8; q++) {
                    float wv = wp[q];
#pragma unroll
                    for (int dy = 0; dy < 2; dy++)
#pragma unroll
                        for (int dx = 0; dx < 2; dx++)
                            acc[dy][dx][q] += v[dy][dx] * wv;
                }
            }
        }
        __syncthreads();
    }
#pragma unroll
    for (int dy = 0; dy < 2; dy++)
#pragma unroll
        for (int dx = 0; dx < 2; dx++) {
            int oy = ty0 + 2 * tyy + dy, ox = tx0 + 2 * txx + dx;
            if (oy < Hout && ox < Wout) {
#pragma unroll
                for (int q = 0; q < 8; q++) {
                    int co = co0 + cog * 8 + q;
                    float r = acc[dy][dx][q];
                    if (do_relu) r = fmaxf(r, 0.f);
                    out[((size_t)n * COUT + co) * Hout * Wout + (size_t)oy * Wout + ox] = r;
                }
            }
        }
}

// ----------------------------------------------------------------------------
// 1x1 heads: obj (3ch) + reg (12ch).
// ----------------------------------------------------------------------------
__global__ __launch_bounds__(256)
void rpn_head_k(const float* __restrict__ t, const float* __restrict__ wobj,
                const float* __restrict__ wreg, float* __restrict__ scores,
                float* __restrict__ deltas)
{
    __shared__ float sw[15][256];
    int tid = threadIdx.x;
    for (int i = tid; i < 15 * 256; i += 256) {
        int k = i >> 8, ci = i & 255;
        sw[k][ci] = (k < 3) ? wobj[k * 256 + ci] : wreg[(k - 3) * 256 + ci];
    }
    __syncthreads();
    int p = blockIdx.x * 256 + tid;
    if (p < NB * 2500) {
        int b = p / 2500, yx = p % 2500;
        float acc[15];
#pragma unroll
        for (int k = 0; k < 15; k++) acc[k] = 0.f;
        const float* tb = t + ((size_t)b * 256) * 2500 + yx;
        for (int ci = 0; ci < 256; ++ci) {
            float v = tb[(size_t)ci * 2500];
#pragma unroll
            for (int k = 0; k < 15; k++) acc[k] += v * sw[k][ci];
        }
#pragma unroll
        for (int k = 0; k < 3; k++)
            scores[(size_t)b * NA + yx * 3 + k] = acc[k];
#pragma unroll
        for (int k = 0; k < 3; k++)
#pragma unroll
            for (int c = 0; c < 4; c++)
                deltas[((size_t)b * NA + (size_t)yx * 3 + k) * 4 + c] = acc[3 + k * 4 + c];
    }
}

// ----------------------------------------------------------------------------
__global__ void decode_k(const float* __restrict__ deltas, float* __restrict__ boxes)
{
    int g = blockIdx.x * 256 + threadIdx.x;
    if (g >= NB * NA) return;
    int a = g % NA;
    int k = a % 3, x = (a / 3) % 50, y = a / 150;
    float s = (k == 0) ? 64.f : (k == 1) ? 128.f : 256.f;
    float cxa = x * 16.f + 8.f, cya = y * 16.f + 8.f;
    const float* d = deltas + (size_t)g * 4;
    float dx = d[0], dy = d[1], dw = d[2], dh = d[3];
    const float clampv = 4.135166556742356f;  // log(1000/16)
    dw = fminf(dw, clampv);
    dh = fminf(dh, clampv);
    float cx = dx * s + cxa, cy = dy * s + cya;
    float w = expf(dw) * s, h = expf(dh) * s;
    float b0 = cx - w * 0.5f, b1 = cy - h * 0.5f;
    float b2 = cx + w * 0.5f, b3 = cy + h * 0.5f;
    float* o = boxes + (size_t)g * 4;
    o[0] = fminf(fmaxf(b0, 0.f), 800.f);
    o[1] = fminf(fmaxf(b1, 0.f), 800.f);
    o[2] = fminf(fmaxf(b2, 0.f), 800.f);
    o[3] = fminf(fmaxf(b3, 0.f), 800.f);
}

// ----------------------------------------------------------------------------
// Top-2000 via bitonic sort of packed keys (desc score, asc index ties).
// ----------------------------------------------------------------------------
__global__ __launch_bounds__(1024)
void topk_k(const float* __restrict__ scores, const float* __restrict__ boxes,
            float* __restrict__ topb)
{
    __shared__ ull key[8192];
    int b = blockIdx.x, tid = threadIdx.x;
    for (int i = tid; i < 8192; i += 1024) {
        ull kv = ~0ull;
        if (i < NA) {
            unsigned u = __float_as_uint(scores[(size_t)b * NA + i]);
            unsigned m = u ^ (((int)u < 0) ? 0xFFFFFFFFu : 0x80000000u);
            kv = ((ull)(~m) << 32) | (unsigned)i;
        }
        key[i] = kv;
    }
    __syncthreads();
    for (int k = 2; k <= 8192; k <<= 1) {
        for (int j = k >> 1; j > 0; j >>= 1) {
            for (int i = tid; i < 8192; i += 1024) {
                int ixj = i ^ j;
                if (ixj > i) {
                    ull a = key[i], c = key[ixj];
                    bool sw = ((i & k) == 0) ? (a > c) : (a < c);
                    if (sw) { key[i] = c; key[ixj] = a; }
                }
            }
            __syncthreads();
        }
    }
    for (int i = tid; i < PRE; i += 1024) {
        int idx = (int)(key[i] & 0xFFFFFFFFull);
#pragma unroll
        for (int c = 0; c < 4; c++)
            topb[((size_t)b * PRE + i) * 4 + c] = boxes[((size_t)b * NA + idx) * 4 + c];
    }
}

// ----------------------------------------------------------------------------
__global__ void iou_mask_k(const float* __restrict__ topb, ull* __restrict__ mask)
{
    int g = blockIdx.x * 256 + threadIdx.x;
    if (g >= NB * PRE * 32) return;
    int b = g / (PRE * 32);
    int r = g % (PRE * 32);
    int i = r >> 5, w = r & 31;
    const float* bi = topb + ((size_t)b * PRE + i) * 4;
    float x1 = bi[0], y1 = bi[1], x2 = bi[2], y2 = bi[3];
    float ai = (x2 - x1) * (y2 - y1);
    ull bits = 0;
    int j0 = w * 64;
    for (int jj = 0; jj < 64; ++jj) {
        int j = j0 + jj;
        if (j >= PRE) break;
        if (j == i) continue;
        const float* bj = topb + ((size_t)b * PRE + j) * 4;
        float xx1 = fmaxf(x1, bj[0]);
        float yy1 = fmaxf(y1, bj[1]);
        float xx2 = fminf(x2, bj[2]);
        float yy2 = fminf(y2, bj[3]);
        float iw = fmaxf(xx2 - xx1, 0.f), ih = fmaxf(yy2 - yy1, 0.f);
        float inter = iw * ih;
        float aj = (bj[2] - bj[0]) * (bj[3] - bj[1]);
        float iou = inter / (ai + aj - inter + 1e-6f);
        if (iou > 0.7f) bits |= (1ull << jj);
    }
    mask[((size_t)b * PRE + i) * 32 + w] = bits;
}

// ----------------------------------------------------------------------------
__global__ __launch_bounds__(64)
void nms_scan_k(const ull* __restrict__ mask, const float* __restrict__ topb,
                float* __restrict__ props)
{
    __shared__ ull rem[32];
    __shared__ int klist[PRE];
    __shared__ int slist[PRE];
    __shared__ int nks;
    int b = blockIdx.x, lane = threadIdx.x;
    if (lane < 32) rem[lane] = 0ull;
    __syncthreads();
    int nk = 0;
    for (int i = 0; i < PRE; ++i) {
        bool keep = ((rem[i >> 6] >> (i & 63)) & 1ull) == 0ull;
        if (keep) {
            if (lane < 32) rem[lane] |= mask[((size_t)b * PRE + i) * 32 + lane];
            if (lane == 0) klist[nk] = i;
            nk++;
        }
        __syncthreads();
    }
    if (lane == 0) {
        int ns = 0;
        for (int i = 0; i < PRE; ++i)
            if ((rem[i >> 6] >> (i & 63)) & 1ull) slist[ns++] = i;
        nks = nk;
    }
    __syncthreads();
    int nkk = nks;
    for (int j = lane; j < POST; j += 64) {
        int kf = (j < nkk) ? klist[j] : slist[j - nkk];
#pragma unroll
        for (int c = 0; c < 4; c++)
            props[((size_t)b * POST + j) * 4 + c] = topb[((size_t)b * PRE + kf) * 4 + c];
    }
}

// ----------------------------------------------------------------------------
// ROI align -> writes flat directly as bf16 (FC1's A operand).
// ----------------------------------------------------------------------------
__global__ __launch_bounds__(256)
void roi_align_k(const float* __restrict__ feat, const float* __restrict__ props,
                 __hip_bfloat16* __restrict__ flat16)
{
    __shared__ int sy0[14], sy1[14], sx0[14], sx1[14];
    __shared__ float swy[14], swx[14];
    int r = blockIdx.x, tid = threadIdx.x;
    int b = r / POST;
    const float* box = props + (size_t)r * 4;
    if (tid < 14) {
        float x1 = box[0] * 0.0625f, y1 = box[1] * 0.0625f;
        float x2 = box[2] * 0.0625f, y2 = box[3] * 0.0625f;
        float bw = (x2 - x1) / 7.0f, bh = (y2 - y1) / 7.0f;
        float off = ((float)tid + 0.5f) * 0.5f;
        float ys = y1 + off * bh;
        float xs = x1 + off * bw;
        float y0f = fminf(fmaxf(floorf(ys), 0.f), 49.f);
        float x0f = fminf(fmaxf(floorf(xs), 0.f), 49.f);
        swy[tid] = fminf(fmaxf(ys - y0f, 0.f), 1.f);
        swx[tid] = fminf(fmaxf(xs - x0f, 0.f), 1.f);
        sy0[tid] = (int)y0f;
        sy1[tid] = min((int)y0f + 1, 49);
        sx0[tid] = (int)x0f;
        sx1[tid] = min((int)x0f + 1, 49);
    }
    __syncthreads();
    const float* fb = feat + (size_t)b * 256 * 2500;
    for (int o = tid; o < 12544; o += 256) {
        int c = o / 49, rem2 = o % 49;
        int py = rem2 / 7, px = rem2 % 7;
        const float* fp = fb + (size_t)c * 2500;
        float s = 0.f;
#pragma unroll
        for (int sy = 0; sy < 2; ++sy) {
            int iy = py * 2 + sy;
            float wy = swy[iy];
            int yr0 = sy0[iy] * 50, yr1 = sy1[iy] * 50;
#pragma unroll
            for (int sx = 0; sx < 2; ++sx) {
                int ix = px * 2 + sx;
                float wx = swx[ix];
                float f00 = fp[yr0 + sx0[ix]];
                float f01 = fp[yr0 + sx1[ix]];
                float f10 = fp[yr1 + sx0[ix]];
                float f11 = fp[yr1 + sx1[ix]];
                s += f00 * (1.f - wy) * (1.f - wx) + f01 * (1.f - wy) * wx
                   + f10 * wy * (1.f - wx) + f11 * wy * wx;
            }
        }
        flat16[(size_t)r * 12544 + o] = __float2bfloat16(s * 0.25f);
    }
}

// ----------------------------------------------------------------------------
// f32 -> bf16 conversion (weights). n must be a multiple of 4.
// ----------------------------------------------------------------------------
__global__ __launch_bounds__(256)
void cvt_bf16_k(const float* __restrict__ in, __hip_bfloat16* __restrict__ out, int n)
{
    int i = (blockIdx.x * 256 + threadIdx.x) * 4;
    if (i < n) {
        float4 v = *reinterpret_cast<const float4*>(&in[i]);
        out[i + 0] = __float2bfloat16(v.x);
        out[i + 1] = __float2bfloat16(v.y);
        out[i + 2] = __float2bfloat16(v.z);
        out[i + 3] = __float2bfloat16(v.w);
    }
}

// ----------------------------------------------------------------------------
// bf16 MFMA GEMM: C[M,N] = relu(A[M,K](bf16) @ W[N,K](bf16)^T + bias).
// 128x128 tile, BK=64, 4 waves (each 64x64 = 4x4 frags of 16x16x32 MFMA).
// Staging via global_load_lds(16B) with XOR granule swizzle applied on the
// GLOBAL source address (linear LDS dest, rule #21); reads apply same XOR.
// ----------------------------------------------------------------------------
template<int OUT_BF16>
__global__ __launch_bounds__(256)
void gemm_mfma_k(const __hip_bfloat16* __restrict__ A,
                 const __hip_bfloat16* __restrict__ W,
                 const float* __restrict__ bias, void* __restrict__ Cout,
                 int M, int N, int K)
{
    __shared__ unsigned short As[128 * 64];
    __shared__ unsigned short Bs[128 * 64];
    const int tid = threadIdx.x;
    const int wid = tid >> 6, lane = tid & 63;
    const int m0 = blockIdx.y * 128, n0 = blockIdx.x * 128;
    const int wr = wid >> 1, wc = wid & 1;

    f32x4 zero = {0.f, 0.f, 0.f, 0.f};
    f32x4 acc[4][4];
#pragma unroll
    for (int m = 0; m < 4; m++)
#pragma unroll
        for (int n = 0; n < 4; n++) acc[m][n] = zero;

    const int srow_base = wid * 32 + (lane >> 3);  // + i*8, covers 32 rows/wave
    const int g_lin = lane & 7;

    const unsigned short* Au = (const unsigned short*)A;
    const unsigned short* Wu = (const unsigned short*)W;

    for (int k0 = 0; k0 < K; k0 += 64) {
#pragma unroll
        for (int i = 0; i < 4; ++i) {
            int r = srow_base + i * 8;
            int g_src = g_lin ^ (r & 7);
            int arow = m0 + r; if (arow >= M) arow = M - 1;
            const unsigned short* gA = Au + (size_t)arow * K + k0 + g_src * 8;
            __builtin_amdgcn_global_load_lds(
                (const GLOBAL_AS unsigned int*)gA,
                (LDS_AS unsigned int*)&As[(wid * 32 + i * 8) * 64], 16, 0, 0);
            int wrow = n0 + r; if (wrow >= N) wrow = N - 1;
            const unsigned short* gW = Wu + (size_t)wrow * K + k0 + g_src * 8;
            __builtin_amdgcn_global_load_lds(
                (const GLOBAL_AS unsigned int*)gW,
                (LDS_AS unsigned int*)&Bs[(wid * 32 + i * 8) * 64], 16, 0, 0);
        }
        __syncthreads();
#pragma unroll
        for (int kh = 0; kh < 2; ++kh) {
            short8v a[4], b[4];
            const int kg = lane >> 4;
#pragma unroll
            for (int m = 0; m < 4; ++m) {
                int r = wr * 64 + m * 16 + (lane & 15);
                int g = (kh * 4 + kg) ^ (r & 7);
                a[m] = *(const short8v*)&As[r * 64 + g * 8];
            }
#pragma unroll
            for (int n = 0; n < 4; ++n) {
                int c = wc * 64 + n * 16 + (lane & 15);
                int g = (kh * 4 + kg) ^ (c & 7);
                b[n] = *(const short8v*)&Bs[c * 64 + g * 8];
            }
#pragma unroll
            for (int m = 0; m < 4; ++m)
#pragma unroll
                for (int n = 0; n < 4; ++n)
                    acc[m][n] = __builtin_amdgcn_mfma_f32_16x16x32_bf16(
                        a[m], b[n], acc[m][n], 0, 0, 0);
        }
        __syncthreads();
    }

#pragma unroll
    for (int n = 0; n < 4; ++n) {
        int col = n0 + wc * 64 + n * 16 + (lane & 15);
        float bv = bias[col];
#pragma unroll
        for (int m = 0; m < 4; ++m) {
#pragma unroll
            for (int q = 0; q < 4; ++q) {
                int row = m0 + wr * 64 + m * 16 + (lane >> 4) * 4 + q;
                if (row < M) {
                    float v = fmaxf(acc[m][n][q] + bv, 0.f);
                    if (OUT_BF16)
                        ((__hip_bfloat16*)Cout)[(size_t)row * N + col] = __float2bfloat16(v);
                    else
                        ((float*)Cout)[(size_t)row * N + col] = v;
                }
            }
        }
    }
}

__global__ void rows_k(float* __restrict__ p)
{
    if (threadIdx.x < NB) p[threadIdx.x] = 1000.0f;
}

// ----------------------------------------------------------------------------
extern "C" void kernel_launch(void* const* d_in, const int* in_sizes, int n_in,
                              void* d_out, int out_size, void* d_ws, size_t ws_size,
                              hipStream_t stream)
{
    const float* images = (const float*)d_in[0];
    const float* W1 = (const float*)d_in[1];
    const float* W2 = (const float*)d_in[2];
    const float* W3 = (const float*)d_in[3];
    const float* W4 = (const float*)d_in[4];
    const float* Wrpn = (const float*)d_in[5];
    const float* Wobj = (const float*)d_in[6];
    const float* Wreg = (const float*)d_in[7];
    const float* Wfc1 = (const float*)d_in[8];
    const float* b1 = (const float*)d_in[9];
    const float* Wfc2 = (const float*)d_in[10];
    const float* b2 = (const float*)d_in[11];
    float* out = (float*)d_out;

    float* ws = (float*)d_ws;
    // Layout (float offsets). Conv buffers alias the flat16 region (dead
    // before roi_align writes flat16). Total ~40.0M floats = 160 MB.
    float* x1b    = ws;                        // 10,240,000
    float* x2b    = ws + 10240000;             //  5,120,000
    float* x3b    = ws + 15360000;             //  2,560,000
    __hip_bfloat16* flat16 = (__hip_bfloat16*)ws;            // 50,176,000 bf16 = 25,088,000 f
    float* feat   = ws + 25088000;             //  2,560,000
    float* t      = ws + 27648000;             //  2,560,000
    __hip_bfloat16* h1_16  = (__hip_bfloat16*)(ws + 30208000);  // 4,096,000 bf16
    __hip_bfloat16* wfc1_16 = (__hip_bfloat16*)(ws + 32256000); // 12,845,056 bf16
    __hip_bfloat16* wfc2_16 = (__hip_bfloat16*)(ws + 38678528); // 1,048,576 bf16
    float* scores = ws + 39202816;             //     30,000
    float* deltas = ws + 39232816;             //    120,000
    float* boxes  = ws + 39352816;             //    120,000
    float* topb   = ws + 39472816;             //     32,000
    ull*   mask   = (ull*)(ws + 39504816);     //    256,000 ull
    float* props  = ws + 40016816;             //     16,000

    // Weight conversions (independent of conv pipeline).
    cvt_bf16_k<<<(12845056 / 4 + 255) / 256, 256, 0, stream>>>(Wfc1, wfc1_16, 12845056);
    cvt_bf16_k<<<(1048576 / 4 + 255) / 256, 256, 0, stream>>>(Wfc2, wfc2_16, 1048576);

    for (int n = 0; n < 4; ++n) {
        conv3x3_k<3, 64, 2, 3><<<dim3(25 * 25, 2, 1), 256, 0, stream>>>(
            images + (size_t)n * 3 * 800 * 800, W1, x1b, 800, 800, 400, 400, 25, 1);
        conv3x3_k<64, 128, 2, 8><<<dim3(13 * 13, 4, 1), 256, 0, stream>>>(
            x1b, W2, x2b, 400, 400, 200, 200, 13, 1);
        conv3x3_k<128, 256, 2, 8><<<dim3(7 * 7, 8, 1), 256, 0, stream>>>(
            x2b, W3, x3b, 200, 200, 100, 100, 7, 1);
        conv3x3_k<256, 256, 2, 8><<<dim3(4 * 4, 8, 1), 256, 0, stream>>>(
            x3b, W4, feat + (size_t)n * 256 * 2500, 100, 100, 50, 50, 4, 1);
    }
    conv3x3_k<256, 256, 1, 8><<<dim3(4 * 4, 8, 4), 256, 0, stream>>>(
        feat, Wrpn, t, 50, 50, 50, 50, 4, 1);
    rpn_head_k<<<40, 256, 0, stream>>>(t, Wobj, Wreg, scores, deltas);
    decode_k<<<(NB * NA + 255) / 256, 256, 0, stream>>>(deltas, boxes);
    topk_k<<<NB, 1024, 0, stream>>>(scores, boxes, topb);
    iou_mask_k<<<(NB * PRE * 32 + 255) / 256, 256, 0, stream>>>(topb, mask);
    nms_scan_k<<<NB, 64, 0, stream>>>(mask, topb, props);
    roi_align_k<<<NB * POST, 256, 0, stream>>>(feat, props, flat16);

    // FC1: 4000x1024 @ K=12544 (bf16 MFMA), out bf16 for FC2.
    gemm_mfma_k<1><<<dim3(8, 32), 256, 0, stream>>>(flat16, wfc1_16, b1, h1_16, 4000, 1024, 12544);
    // FC2: 4000x1024 @ K=1024, out f32 to d_out.
    gemm_mfma_k<0><<<dim3(8, 32), 256, 0, stream>>>(h1_16, wfc2_16, b2, out, 4000, 1024, 1024);
    rows_k<<<1, 64, 0, stream>>>(out + 4096000);
}

// Round 8
// 1326.290 us; speedup vs baseline: 6.7544x; 5.6014x over previous
//
#include <hip/hip_runtime.h>
#include <hip/hip_bf16.h>
#include <cstdint>

using ull = unsigned long long;

#define NB 4
#define NA 7500
#define PRE 2000
#define POST 1000

typedef __attribute__((ext_vector_type(8))) short short8v;
typedef __attribute__((ext_vector_type(4))) float f32x4;

#define GLOBAL_AS __attribute__((address_space(1)))
#define LDS_AS __attribute__((address_space(3)))

__device__ inline float bf2f(unsigned short u) { return __uint_as_float(((unsigned)u) << 16); }
__device__ inline unsigned short f2bf(float f) {
    __hip_bfloat16 h = __float2bfloat16(f);
    return *(unsigned short*)&h;
}

// ----------------------------------------------------------------------------
// conv1: 3->64ch, stride 2, pad 1, relu. f32 compute (K=27 too small for MFMA),
// output NHWC bf16 (400x400x64). Input NCHW f32 image (offset passed).
// ----------------------------------------------------------------------------
__global__ __launch_bounds__(256)
void conv1_k(const float* __restrict__ in, const float* __restrict__ w,
             unsigned short* __restrict__ out)
{
    __shared__ float s_in[3][33][34];
    __shared__ float s_w[3][9][32];
    const int tid = threadIdx.x;
    const int txx = tid & 7, tyy = (tid >> 3) & 7, cog = tid >> 6;
    const int ty0 = (blockIdx.x / 25) * 16, tx0 = (blockIdx.x % 25) * 16;
    const int co0 = blockIdx.y * 32;

    float acc[2][2][8];
#pragma unroll
    for (int a = 0; a < 2; a++)
#pragma unroll
        for (int b = 0; b < 2; b++)
#pragma unroll
            for (int q = 0; q < 8; q++) acc[a][b][q] = 0.f;

    for (int idx = tid; idx < 3 * 33 * 33; idx += 256) {
        int ci = idx / (33 * 33);
        int rr = (idx / 33) % 33;
        int cc = idx % 33;
        int gy = ty0 * 2 - 1 + rr;
        int gx = tx0 * 2 - 1 + cc;
        float v = 0.f;
        if ((unsigned)gy < 800u && (unsigned)gx < 800u)
            v = in[(size_t)ci * 640000 + (size_t)gy * 800 + gx];
        s_in[ci][rr][cc] = v;
    }
    for (int idx = tid; idx < 3 * 9 * 32; idx += 256) {
        int co = idx & 31;
        int rest = idx >> 5;
        int kk = rest % 9, ci = rest / 9;
        s_w[ci][kk][co] = w[((size_t)(co0 + co) * 3 + ci) * 9 + kk];
    }
    __syncthreads();
#pragma unroll
    for (int ci = 0; ci < 3; ++ci) {
#pragma unroll
        for (int kk = 0; kk < 9; ++kk) {
            const int ky = kk / 3, kx = kk % 3;
            float v[2][2];
#pragma unroll
            for (int dy = 0; dy < 2; dy++)
#pragma unroll
                for (int dx = 0; dx < 2; dx++)
                    v[dy][dx] = s_in[ci][(2 * tyy + dy) * 2 + ky][(2 * txx + dx) * 2 + kx];
            const float* wp = &s_w[ci][kk][cog * 8];
#pragma unroll
            for (int q = 0; q < 8; q++) {
                float wv = wp[q];
#pragma unroll
                for (int dy = 0; dy < 2; dy++)
#pragma unroll
                    for (int dx = 0; dx < 2; dx++)
                        acc[dy][dx][q] += v[dy][dx] * wv;
            }
        }
    }
#pragma unroll
    for (int dy = 0; dy < 2; dy++)
#pragma unroll
        for (int dx = 0; dx < 2; dx++) {
            int oy = ty0 + 2 * tyy + dy, ox = tx0 + 2 * txx + dx;
            short8v t;
#pragma unroll
            for (int q = 0; q < 8; q++) t[q] = (short)f2bf(fmaxf(acc[dy][dx][q], 0.f));
            *(short8v*)&out[((size_t)oy * 400 + ox) * 64 + co0 + cog * 8] = t;
        }
}

// ----------------------------------------------------------------------------
// Pack conv weights OIHW f32 -> blocked bf16:
// blob i = (((ct*CH + cc)*9 + tap)*128 + co)*4 + slot ; slot holds kg = slot^((co>>1)&3)
// ----------------------------------------------------------------------------
__global__ __launch_bounds__(256)
void pack_conv_k(const float* __restrict__ w, unsigned short* __restrict__ dst,
                 int CIN, int CH, int nblob)
{
    int i = blockIdx.x * 256 + threadIdx.x;
    if (i >= nblob) return;
    int slot = i & 3;
    int co = (i >> 2) & 127;
    int j2 = i >> 9;
    int tap = j2 % 9;
    int j3 = j2 / 9;
    int cc = j3 % CH;
    int ct = j3 / CH;
    int kg = slot ^ ((co >> 1) & 3);
    int cog = ct * 128 + co;
    short8v t;
#pragma unroll
    for (int j = 0; j < 8; ++j) {
        int ci = cc * 32 + kg * 8 + j;
        t[j] = (short)f2bf(w[((size_t)cog * CIN + ci) * 9 + tap]);
    }
    *(short8v*)&dst[(size_t)i * 8] = t;
}

// ----------------------------------------------------------------------------
// Implicit-GEMM MFMA conv: 3x3, pad 1, stride S, relu. NHWC bf16 in/out.
// Tile: 8 output rows x 16 cols x 128 co. 4 waves, each 4 rows x 64 co
// (4x4 frags of 16x16x32). A staged reg->LDS with zero-pad + XOR slot
// swizzle; B staged linear via global_load_lds (swizzle pre-baked by pack).
// ----------------------------------------------------------------------------
template<int CIN, int COUT, int S>
__global__ __launch_bounds__(256)
void conv_mfma_k(const unsigned short* __restrict__ in,
                 const unsigned short* __restrict__ wpk,
                 unsigned short* __restrict__ out,
                 int Hin, int Win, int Hout, int Wout, int ntx,
                 size_t in_stride, size_t out_stride)
{
    constexpr int CH = CIN / 32;
    constexpr int RW = 15 * S + 3;
    constexpr int RH = 7 * S + 3;
    __shared__ __align__(16) unsigned short Alds[RH * RW * 32];
    __shared__ __align__(16) unsigned short Blds[9 * 128 * 32];

    const int tid = threadIdx.x;
    const int wid = tid >> 6, lane = tid & 63;
    const int x15 = lane & 15, kg = lane >> 4;
    const int wr = wid >> 1, wc = wid & 1;
    const int ty = blockIdx.x / ntx, tx = blockIdx.x % ntx;
    const int oy0 = ty * 8, ox0 = tx * 16;
    const int ct = blockIdx.y;
    in += blockIdx.z * in_stride;
    out += blockIdx.z * out_stride;
    const unsigned short* wbase = wpk + (size_t)ct * CH * 9 * 128 * 32;
    const int gy0 = oy0 * S - 1, gx0 = ox0 * S - 1;

    f32x4 acc[4][4];
#pragma unroll
    for (int m = 0; m < 4; m++)
#pragma unroll
        for (int n = 0; n < 4; n++) acc[m][n] = (f32x4){0.f, 0.f, 0.f, 0.f};

    for (int cc = 0; cc < CH; ++cc) {
        // --- stage A (zero-padded, slot-swizzled) ---
        for (int idx = tid; idx < RH * RW * 4; idx += 256) {
            int q = idx & 3, pi = idx >> 2;
            int iy = pi / RW, ix = pi - iy * RW;
            int gy = gy0 + iy, gx = gx0 + ix;
            int g = q ^ ((ix >> 1) & 3);
            short8v v = {0, 0, 0, 0, 0, 0, 0, 0};
            if ((unsigned)gy < (unsigned)Hin && (unsigned)gx < (unsigned)Win)
                v = *(const short8v*)&in[((size_t)gy * Win + gx) * CIN + cc * 32 + g * 8];
            *(short8v*)&Alds[(size_t)idx * 8] = v;
        }
        // --- stage B (linear copy, 72 KiB) ---
        const unsigned short* bsrc = wbase + (size_t)cc * 9 * 128 * 32;
#pragma unroll
        for (int p = 0; p < 18; ++p) {
            __builtin_amdgcn_global_load_lds(
                (const GLOBAL_AS unsigned int*)(bsrc + ((size_t)(p * 4 + wid) * 64 + lane) * 8),
                (LDS_AS unsigned int*)&Blds[(p * 4 + wid) * 512], 16, 0, 0);
        }
        __syncthreads();
        // --- 9 taps x 16 MFMA per wave ---
#pragma unroll
        for (int tap = 0; tap < 9; ++tap) {
            const int ky = tap / 3, kx = tap - ky * 3;
            short8v a[4], b[4];
            const int ix = x15 * S + kx;
            const int aslot = kg ^ ((ix >> 1) & 3);
#pragma unroll
            for (int m = 0; m < 4; ++m) {
                int iy = (wr * 4 + m) * S + ky;
                a[m] = *(const short8v*)&Alds[((iy * RW + ix) * 4 + aslot) * 8];
            }
#pragma unroll
            for (int n = 0; n < 4; ++n) {
                int co = wc * 64 + n * 16 + x15;
                int bslot = kg ^ ((co >> 1) & 3);
                b[n] = *(const short8v*)&Blds[((tap * 128 + co) * 4 + bslot) * 8];
            }
#pragma unroll
            for (int m = 0; m < 4; ++m)
#pragma unroll
                for (int n = 0; n < 4; ++n)
                    acc[m][n] = __builtin_amdgcn_mfma_f32_16x16x32_bf16(a[m], b[n], acc[m][n], 0, 0, 0);
        }
        __syncthreads();
    }
    // --- store: C row = ox offset ((lane>>4)*4+q), col = co offset (lane&15) ---
#pragma unroll
    for (int m = 0; m < 4; ++m) {
        int oy = oy0 + wr * 4 + m;
        if (oy >= Hout) continue;
#pragma unroll
        for (int q = 0; q < 4; ++q) {
            int ox = ox0 + (lane >> 4) * 4 + q;
            if (ox >= Wout) continue;
            size_t po = ((size_t)oy * Wout + ox) * COUT + (size_t)ct * 128 + wc * 64 + x15;
#pragma unroll
            for (int n = 0; n < 4; ++n)
                out[po + n * 16] = f2bf(fmaxf(acc[m][n][q], 0.f));
        }
    }
}

// ----------------------------------------------------------------------------
// 1x1 heads from NHWC bf16 t: obj(3) + reg(12).
// ----------------------------------------------------------------------------
__global__ __launch_bounds__(256)
void rpn_head_k(const unsigned short* __restrict__ t16, const float* __restrict__ wobj,
                const float* __restrict__ wreg, float* __restrict__ scores,
                float* __restrict__ deltas)
{
    __shared__ float sw[15][256];
    int tid = threadIdx.x;
    for (int i = tid; i < 15 * 256; i += 256) {
        int k = i >> 8, ci = i & 255;
        sw[k][ci] = (k < 3) ? wobj[k * 256 + ci] : wreg[(k - 3) * 256 + ci];
    }
    __syncthreads();
    int p = blockIdx.x * 256 + tid;
    if (p >= NB * 2500) return;
    int b = p / 2500, yx = p - b * 2500;
    const unsigned short* tp = t16 + ((size_t)b * 2500 + yx) * 256;
    float acc[15];
#pragma unroll
    for (int k = 0; k < 15; k++) acc[k] = 0.f;
    for (int g = 0; g < 32; ++g) {
        short8v v8 = *(const short8v*)&tp[g * 8];
#pragma unroll
        for (int j = 0; j < 8; ++j) {
            float v = bf2f((unsigned short)v8[j]);
#pragma unroll
            for (int k = 0; k < 15; k++) acc[k] += v * sw[k][g * 8 + j];
        }
    }
#pragma unroll
    for (int k = 0; k < 3; k++)
        scores[(size_t)b * NA + yx * 3 + k] = acc[k];
#pragma unroll
    for (int k = 0; k < 3; k++)
#pragma unroll
        for (int c = 0; c < 4; c++)
            deltas[((size_t)b * NA + (size_t)yx * 3 + k) * 4 + c] = acc[3 + k * 4 + c];
}

// ----------------------------------------------------------------------------
__global__ void decode_k(const float* __restrict__ deltas, float* __restrict__ boxes)
{
    int g = blockIdx.x * 256 + threadIdx.x;
    if (g >= NB * NA) return;
    int a = g % NA;
    int k = a % 3, x = (a / 3) % 50, y = a / 150;
    float s = (k == 0) ? 64.f : (k == 1) ? 128.f : 256.f;
    float cxa = x * 16.f + 8.f, cya = y * 16.f + 8.f;
    const float* d = deltas + (size_t)g * 4;
    float dx = d[0], dy = d[1], dw = d[2], dh = d[3];
    const float clampv = 4.135166556742356f;  // log(1000/16)
    dw = fminf(dw, clampv);
    dh = fminf(dh, clampv);
    float cx = dx * s + cxa, cy = dy * s + cya;
    float w = expf(dw) * s, h = expf(dh) * s;
    float b0 = cx - w * 0.5f, b1 = cy - h * 0.5f;
    float b2 = cx + w * 0.5f, b3 = cy + h * 0.5f;
    float* o = boxes + (size_t)g * 4;
    o[0] = fminf(fmaxf(b0, 0.f), 800.f);
    o[1] = fminf(fmaxf(b1, 0.f), 800.f);
    o[2] = fminf(fmaxf(b2, 0.f), 800.f);
    o[3] = fminf(fmaxf(b3, 0.f), 800.f);
}

// ----------------------------------------------------------------------------
// Top-2000 via bitonic sort of packed keys (desc score, asc index ties).
// ----------------------------------------------------------------------------
__global__ __launch_bounds__(1024)
void topk_k(const float* __restrict__ scores, const float* __restrict__ boxes,
            float* __restrict__ topb)
{
    __shared__ ull key[8192];
    int b = blockIdx.x, tid = threadIdx.x;
    for (int i = tid; i < 8192; i += 1024) {
        ull kv = ~0ull;
        if (i < NA) {
            unsigned u = __float_as_uint(scores[(size_t)b * NA + i]);
            unsigned m = u ^ (((int)u < 0) ? 0xFFFFFFFFu : 0x80000000u);
            kv = ((ull)(~m) << 32) | (unsigned)i;
        }
        key[i] = kv;
    }
    __syncthreads();
    for (int k = 2; k <= 8192; k <<= 1) {
        for (int j = k >> 1; j > 0; j >>= 1) {
            for (int i = tid; i < 8192; i += 1024) {
                int ixj = i ^ j;
                if (ixj > i) {
                    ull a = key[i], c = key[ixj];
                    bool sw = ((i & k) == 0) ? (a > c) : (a < c);
                    if (sw) { key[i] = c; key[ixj] = a; }
                }
            }
            __syncthreads();
        }
    }
    for (int i = tid; i < PRE; i += 1024) {
        int idx = (int)(key[i] & 0xFFFFFFFFull);
#pragma unroll
        for (int c = 0; c < 4; c++)
            topb[((size_t)b * PRE + i) * 4 + c] = boxes[((size_t)b * NA + idx) * 4 + c];
    }
}

// ----------------------------------------------------------------------------
__global__ void iou_mask_k(const float* __restrict__ topb, ull* __restrict__ mask)
{
    int g = blockIdx.x * 256 + threadIdx.x;
    if (g >= NB * PRE * 32) return;
    int b = g / (PRE * 32);
    int r = g % (PRE * 32);
    int i = r >> 5, w = r & 31;
    const float* bi = topb + ((size_t)b * PRE + i) * 4;
    float x1 = bi[0], y1 = bi[1], x2 = bi[2], y2 = bi[3];
    float ai = (x2 - x1) * (y2 - y1);
    ull bits = 0;
    int j0 = w * 64;
    for (int jj = 0; jj < 64; ++jj) {
        int j = j0 + jj;
        if (j >= PRE) break;
        if (j == i) continue;
        const float* bj = topb + ((size_t)b * PRE + j) * 4;
        float xx1 = fmaxf(x1, bj[0]);
        float yy1 = fmaxf(y1, bj[1]);
        float xx2 = fminf(x2, bj[2]);
        float yy2 = fminf(y2, bj[3]);
        float iw = fmaxf(xx2 - xx1, 0.f), ih = fmaxf(yy2 - yy1, 0.f);
        float inter = iw * ih;
        float aj = (bj[2] - bj[0]) * (bj[3] - bj[1]);
        float iou = inter / (ai + aj - inter + 1e-6f);
        if (iou > 0.7f) bits |= (1ull << jj);
    }
    mask[((size_t)b * PRE + i) * 32 + w] = bits;
}

// ----------------------------------------------------------------------------
// Greedy NMS scan: 1 wave/batch, barrier-free scan. rem word l on lane l;
// keep-bit via __shfl broadcast; depth-16 register prefetch of mask rows.
// Then parallel suppressed-list via popcount prefix; emit 1000 props.
// ----------------------------------------------------------------------------
__global__ __launch_bounds__(64)
void nms_scan_k(const ull* __restrict__ mask, const float* __restrict__ topb,
                float* __restrict__ props)
{
    __shared__ int klist[PRE];
    __shared__ int slist[PRE];
    int b = blockIdx.x, lane = threadIdx.x;
    const ull* M = mask + (size_t)b * PRE * 32;
    const bool ld = lane < 32;
    ull cur[16], nxt[16];
#pragma unroll
    for (int j = 0; j < 16; ++j) cur[j] = ld ? M[(size_t)j * 32 + lane] : 0ull;
    ull rem = 0ull;
    int nk = 0;
    for (int i0 = 0; i0 < PRE; i0 += 16) {
        if (i0 + 16 < PRE) {
#pragma unroll
            for (int j = 0; j < 16; ++j)
                nxt[j] = ld ? M[(size_t)(i0 + 16 + j) * 32 + lane] : 0ull;
        } else {
#pragma unroll
            for (int j = 0; j < 16; ++j) nxt[j] = 0ull;
        }
#pragma unroll
        for (int j = 0; j < 16; ++j) {
            int i = i0 + j;
            ull rw = __shfl(rem, i >> 6);
            bool keep = ((rw >> (i & 63)) & 1ull) == 0ull;
            if (keep) {
                rem |= cur[j];
                if (lane == 0) klist[nk] = i;
                nk++;
            }
        }
#pragma unroll
        for (int j = 0; j < 16; ++j) cur[j] = nxt[j];
    }
    // suppressed indices ascending
    int cnt = ld ? __popcll(rem) : 0;
    int pre = cnt;
    for (int off = 1; off < 64; off <<= 1) {
        int o = __shfl_up(pre, off);
        if (lane >= off) pre += o;
    }
    int base = pre - cnt;
    if (ld) {
        ull r = rem;
        int pos = base;
        while (r) {
            int bnum = __ffsll((unsigned long long)r) - 1;
            slist[pos++] = lane * 64 + bnum;
            r &= r - 1;
        }
    }
    __syncthreads();
    for (int j = lane; j < POST; j += 64) {
        int kf = (j < nk) ? klist[j] : slist[j - nk];
#pragma unroll
        for (int c = 0; c < 4; c++)
            props[((size_t)b * POST + j) * 4 + c] = topb[((size_t)b * PRE + kf) * 4 + c];
    }
}

// ----------------------------------------------------------------------------
// ROI align from NHWC bf16 feat -> flat16 pixel-major: flat[r][s*256+c].
// ----------------------------------------------------------------------------
__global__ __launch_bounds__(256)
void roi_align_k(const unsigned short* __restrict__ feat16, const float* __restrict__ props,
                 unsigned short* __restrict__ flat16)
{
    __shared__ int sy0[14], sy1[14], sx0[14], sx1[14];
    __shared__ float swy[14], swx[14];
    int r = blockIdx.x, tid = threadIdx.x;
    int b = r / POST;
    const float* box = props + (size_t)r * 4;
    if (tid < 14) {
        float x1 = box[0] * 0.0625f, y1 = box[1] * 0.0625f;
        float x2 = box[2] * 0.0625f, y2 = box[3] * 0.0625f;
        float bw = (x2 - x1) / 7.0f, bh = (y2 - y1) / 7.0f;
        float off = ((float)tid + 0.5f) * 0.5f;
        float ys = y1 + off * bh;
        float xs = x1 + off * bw;
        float y0f = fminf(fmaxf(floorf(ys), 0.f), 49.f);
        float x0f = fminf(fmaxf(floorf(xs), 0.f), 49.f);
        swy[tid] = fminf(fmaxf(ys - y0f, 0.f), 1.f);
        swx[tid] = fminf(fmaxf(xs - x0f, 0.f), 1.f);
        sy0[tid] = (int)y0f;
        sy1[tid] = min((int)y0f + 1, 49);
        sx0[tid] = (int)x0f;
        sx1[tid] = min((int)x0f + 1, 49);
    }
    __syncthreads();
    const unsigned short* fb = feat16 + (size_t)b * 2500 * 256;
    for (int o = tid; o < 49 * 32; o += 256) {
        int bin = o >> 5, cg = o & 31;
        int py = bin / 7, px = bin - py * 7;
        float av[8];
#pragma unroll
        for (int j = 0; j < 8; j++) av[j] = 0.f;
#pragma unroll
        for (int sy = 0; sy < 2; ++sy) {
            int iy = py * 2 + sy;
            float wy = swy[iy];
            int y0 = sy0[iy], y1 = sy1[iy];
#pragma unroll
            for (int sx = 0; sx < 2; ++sx) {
                int ix = px * 2 + sx;
                float wx = swx[ix];
                int x0 = sx0[ix], x1 = sx1[ix];
                short8v v00 = *(const short8v*)&fb[((size_t)y0 * 50 + x0) * 256 + cg * 8];
                short8v v01 = *(const short8v*)&fb[((size_t)y0 * 50 + x1) * 256 + cg * 8];
                short8v v10 = *(const short8v*)&fb[((size_t)y1 * 50 + x0) * 256 + cg * 8];
                short8v v11 = *(const short8v*)&fb[((size_t)y1 * 50 + x1) * 256 + cg * 8];
                float w00 = (1.f - wy) * (1.f - wx), w01 = (1.f - wy) * wx;
                float w10 = wy * (1.f - wx), w11 = wy * wx;
#pragma unroll
                for (int j = 0; j < 8; j++)
                    av[j] += w00 * bf2f((unsigned short)v00[j]) + w01 * bf2f((unsigned short)v01[j])
                           + w10 * bf2f((unsigned short)v10[j]) + w11 * bf2f((unsigned short)v11[j]);
            }
        }
        short8v t;
#pragma unroll
        for (int j = 0; j < 8; j++) t[j] = (short)f2bf(av[j] * 0.25f);
        *(short8v*)&flat16[(size_t)r * 12544 + bin * 256 + cg * 8] = t;
    }
}

// ----------------------------------------------------------------------------
// Pack Wfc1 with the flat permutation: dst[n][s*256+c] = W[n][c*49+s], bf16.
// LDS-transpose per n-row (coalesced read AND write).
// ----------------------------------------------------------------------------
__global__ __launch_bounds__(256)
void pack_fc1_k(const float* __restrict__ W, unsigned short* __restrict__ dst)
{
    __shared__ float row[12544];
    int n = blockIdx.x, tid = threadIdx.x;
    for (int i = tid; i < 12544; i += 256) row[i] = W[(size_t)n * 12544 + i];
    __syncthreads();
    for (int o = tid; o < 1568; o += 256) {
        int s = o >> 5, cg = o & 31;
        short8v t;
#pragma unroll
        for (int j = 0; j < 8; ++j) t[j] = (short)f2bf(row[(cg * 8 + j) * 49 + s]);
        *(short8v*)&dst[(size_t)n * 12544 + s * 256 + cg * 8] = t;
    }
}

// ----------------------------------------------------------------------------
__global__ __launch_bounds__(256)
void cvt_bf16_k(const float* __restrict__ in, unsigned short* __restrict__ out, int n)
{
    int i = (blockIdx.x * 256 + threadIdx.x) * 4;
    if (i < n) {
        float4 v = *reinterpret_cast<const float4*>(&in[i]);
        out[i + 0] = f2bf(v.x);
        out[i + 1] = f2bf(v.y);
        out[i + 2] = f2bf(v.z);
        out[i + 3] = f2bf(v.w);
    }
}

// ----------------------------------------------------------------------------
// bf16 MFMA GEMM: C[M,N] = relu(A[M,K] @ W[N,K]^T + bias). (round-4, verified)
// ----------------------------------------------------------------------------
template<int OUT_BF16>
__global__ __launch_bounds__(256)
void gemm_mfma_k(const unsigned short* __restrict__ Au,
                 const unsigned short* __restrict__ Wu,
                 const float* __restrict__ bias, void* __restrict__ Cout,
                 int M, int N, int K)
{
    __shared__ unsigned short As[128 * 64];
    __shared__ unsigned short Bs[128 * 64];
    const int tid = threadIdx.x;
    const int wid = tid >> 6, lane = tid & 63;
    const int m0 = blockIdx.y * 128, n0 = blockIdx.x * 128;
    const int wr = wid >> 1, wc = wid & 1;

    f32x4 acc[4][4];
#pragma unroll
    for (int m = 0; m < 4; m++)
#pragma unroll
        for (int n = 0; n < 4; n++) acc[m][n] = (f32x4){0.f, 0.f, 0.f, 0.f};

    const int srow_base = wid * 32 + (lane >> 3);
    const int g_lin = lane & 7;

    for (int k0 = 0; k0 < K; k0 += 64) {
#pragma unroll
        for (int i = 0; i < 4; ++i) {
            int r = srow_base + i * 8;
            int g_src = g_lin ^ (r & 7);
            int arow = m0 + r; if (arow >= M) arow = M - 1;
            const unsigned short* gA = Au + (size_t)arow * K + k0 + g_src * 8;
            __builtin_amdgcn_global_load_lds(
                (const GLOBAL_AS unsigned int*)gA,
                (LDS_AS unsigned int*)&As[(wid * 32 + i * 8) * 64], 16, 0, 0);
            int wrow = n0 + r; if (wrow >= N) wrow = N - 1;
            const unsigned short* gW = Wu + (size_t)wrow * K + k0 + g_src * 8;
            __builtin_amdgcn_global_load_lds(
                (const GLOBAL_AS unsigned int*)gW,
                (LDS_AS unsigned int*)&Bs[(wid * 32 + i * 8) * 64], 16, 0, 0);
        }
        __syncthreads();
#pragma unroll
        for (int kh = 0; kh < 2; ++kh) {
            short8v a[4], b[4];
            const int kg = lane >> 4;
#pragma unroll
            for (int m = 0; m < 4; ++m) {
                int r = wr * 64 + m * 16 + (lane & 15);
                int g = (kh * 4 + kg) ^ (r & 7);
                a[m] = *(const short8v*)&As[r * 64 + g * 8];
            }
#pragma unroll
            for (int n = 0; n < 4; ++n) {
                int c = wc * 64 + n * 16 + (lane & 15);
                int g = (kh * 4 + kg) ^ (c & 7);
                b[n] = *(const short8v*)&Bs[c * 64 + g * 8];
            }
#pragma unroll
            for (int m = 0; m < 4; ++m)
#pragma unroll
                for (int n = 0; n < 4; ++n)
                    acc[m][n] = __builtin_amdgcn_mfma_f32_16x16x32_bf16(a[m], b[n], acc[m][n], 0, 0, 0);
        }
        __syncthreads();
    }

#pragma unroll
    for (int n = 0; n < 4; ++n) {
        int col = n0 + wc * 64 + n * 16 + (lane & 15);
        float bv = bias[col];
#pragma unroll
        for (int m = 0; m < 4; ++m) {
#pragma unroll
            for (int q = 0; q < 4; ++q) {
                int row = m0 + wr * 64 + m * 16 + (lane >> 4) * 4 + q;
                if (row < M) {
                    float v = fmaxf(acc[m][n][q] + bv, 0.f);
                    if (OUT_BF16)
                        ((unsigned short*)Cout)[(size_t)row * N + col] = f2bf(v);
                    else
                        ((float*)Cout)[(size_t)row * N + col] = v;
                }
            }
        }
    }
}

__global__ void rows_k(float* __restrict__ p)
{
    if (threadIdx.x < NB) p[threadIdx.x] = 1000.0f;
}

// ----------------------------------------------------------------------------
extern "C" void kernel_launch(void* const* d_in, const int* in_sizes, int n_in,
                              void* d_out, int out_size, void* d_ws, size_t ws_size,
                              hipStream_t stream)
{
    const float* images = (const float*)d_in[0];
    const float* W1 = (const float*)d_in[1];
    const float* W2 = (const float*)d_in[2];
    const float* W3 = (const float*)d_in[3];
    const float* W4 = (const float*)d_in[4];
    const float* Wrpn = (const float*)d_in[5];
    const float* Wobj = (const float*)d_in[6];
    const float* Wreg = (const float*)d_in[7];
    const float* Wfc1 = (const float*)d_in[8];
    const float* b1 = (const float*)d_in[9];
    const float* Wfc2 = (const float*)d_in[10];
    const float* b2 = (const float*)d_in[11];
    float* out = (float*)d_out;

    float* ws = (float*)d_ws;
    // Layout (float offsets). Per-image conv buffers alias the flat16 region
    // (dead before roi_align writes). Total 38,246,960 f = 153 MB.
    unsigned short* flat16 = (unsigned short*)ws;              // 50,176,000 bf16
    unsigned short* x1b16  = (unsigned short*)ws;              // 10,240,000 bf16 (400*400*64)
    unsigned short* x2b16  = (unsigned short*)(ws + 5120000);  //  5,120,000 bf16
    unsigned short* x3b16  = (unsigned short*)(ws + 7680000);  //  2,560,000 bf16
    unsigned short* feat16 = (unsigned short*)(ws + 25088000); //  2,560,000 bf16 (4 imgs)
    unsigned short* t16    = (unsigned short*)(ws + 26368000); //  2,560,000 bf16
    unsigned short* h1_16  = (unsigned short*)(ws + 27648000); //  4,096,000 bf16
    unsigned short* wfc1_16 = (unsigned short*)(ws + 29696000); // 12,845,056 bf16
    unsigned short* wfc2_16 = (unsigned short*)(ws + 36118528); //  1,048,576 bf16
    unsigned short* wconvp  = (unsigned short*)(ws + 36642816); //  1,548,288 bf16
    unsigned short* w2p   = wconvp;
    unsigned short* w3p   = wconvp + 73728;
    unsigned short* w4p   = wconvp + 368640;
    unsigned short* wrpnp = wconvp + 958464;
    float* scores = ws + 37416960;
    float* deltas = ws + 37446960;
    float* boxes  = ws + 37566960;
    float* topb   = ws + 37686960;
    ull*   mask   = (ull*)(ws + 37718960);
    float* props  = ws + 38230960;

    // Weight packing (independent of conv pipeline).
    pack_fc1_k<<<1024, 256, 0, stream>>>(Wfc1, wfc1_16);
    cvt_bf16_k<<<(1048576 / 4 + 255) / 256, 256, 0, stream>>>(Wfc2, wfc2_16, 1048576);
    pack_conv_k<<<(9216 + 255) / 256, 256, 0, stream>>>(W2, w2p, 64, 2, 9216);
    pack_conv_k<<<(36864 + 255) / 256, 256, 0, stream>>>(W3, w3p, 128, 4, 36864);
    pack_conv_k<<<(73728 + 255) / 256, 256, 0, stream>>>(W4, w4p, 256, 8, 73728);
    pack_conv_k<<<(73728 + 255) / 256, 256, 0, stream>>>(Wrpn, wrpnp, 256, 8, 73728);

    for (int n = 0; n < 4; ++n) {
        conv1_k<<<dim3(625, 2, 1), 256, 0, stream>>>(
            images + (size_t)n * 3 * 800 * 800, W1, x1b16);
        conv_mfma_k<64, 128, 2><<<dim3(325, 1, 1), 256, 0, stream>>>(
            x1b16, w2p, x2b16, 400, 400, 200, 200, 13, 0, 0);
        conv_mfma_k<128, 256, 2><<<dim3(91, 2, 1), 256, 0, stream>>>(
            x2b16, w3p, x3b16, 200, 200, 100, 100, 7, 0, 0);
        conv_mfma_k<256, 256, 2><<<dim3(28, 2, 1), 256, 0, stream>>>(
            x3b16, w4p, feat16 + (size_t)n * 640000, 100, 100, 50, 50, 4, 0, 0);
    }
    conv_mfma_k<256, 256, 1><<<dim3(28, 2, 4), 256, 0, stream>>>(
        feat16, wrpnp, t16, 50, 50, 50, 50, 4, 640000, 640000);

    rpn_head_k<<<40, 256, 0, stream>>>(t16, Wobj, Wreg, scores, deltas);
    decode_k<<<(NB * NA + 255) / 256, 256, 0, stream>>>(deltas, boxes);
    topk_k<<<NB, 1024, 0, stream>>>(scores, boxes, topb);
    iou_mask_k<<<(NB * PRE * 32 + 255) / 256, 256, 0, stream>>>(topb, mask);
    nms_scan_k<<<NB, 64, 0, stream>>>(mask, topb, props);
    roi_align_k<<<NB * POST, 256, 0, stream>>>(feat16, props, flat16);

    gemm_mfma_k<1><<<dim3(8, 32), 256, 0, stream>>>(flat16, wfc1_16, b1, h1_16, 4000, 1024, 12544);
    gemm_mfma_k<0><<<dim3(8, 32), 256, 0, stream>>>(h1_16, wfc2_16, b2, out, 4000, 1024, 1024);
    rows_k<<<1, 64, 0, stream>>>(out + 4096000);
}